// Round 9
// baseline (312.880 us; speedup 1.0000x reference)
//
#include <hip/hip_runtime.h>

typedef unsigned short u16;
typedef __attribute__((ext_vector_type(8))) short bf16x8;
typedef __attribute__((ext_vector_type(8))) unsigned short u16x8;
typedef __attribute__((ext_vector_type(4))) float f32x4;
typedef __attribute__((ext_vector_type(4))) unsigned short u16x4;
typedef __attribute__((ext_vector_type(2))) unsigned int u32x2;
typedef __attribute__((ext_vector_type(4))) unsigned int u32x4;

#define Bn 8
#define Tn 4096
#define Cn 1024
#define HSn 128

#define SBAR __builtin_amdgcn_sched_barrier(0)

__device__ __forceinline__ float bf2f(u16 b) {
    unsigned u = ((unsigned)b) << 16;
    return __builtin_bit_cast(float, u);
}
// HW packed f32->bf16 (RNE), 1 VALU op for 2 values. No builtin on gfx950.
__device__ __forceinline__ unsigned cvt_pk_bf16(float a, float b) {
    unsigned r;
    asm("v_cvt_pk_bf16_f32 %0, %1, %2" : "=v"(r) : "v"(a), "v"(b));
    return r;
}
__device__ __forceinline__ u16 f2bf(float f) { return (u16)cvt_pk_bf16(f, f); }

// Forced-register 16B global load. asm volatile + named dest consumed later
// => the register allocator MUST keep it live (compiler was silently
// deleting intrinsic-level register prefetch: r7/r8 VGPR_Count=112/116 vs
// required >=168). vmcnt for these is managed MANUALLY.
__device__ __forceinline__ u32x4 gld16(const u16* p) {
    u32x4 d;
    asm volatile("global_load_dwordx4 %0, %1, off" : "=&v"(d) : "v"(p));
    return d;
}

// Workgroup barrier WITHOUT vmcnt drain: LDS visibility needs lgkmcnt(0) only.
__device__ __forceinline__ void wg_barrier() {
    __builtin_amdgcn_sched_barrier(0);
    asm volatile("s_waitcnt lgkmcnt(0)" ::: "memory");
    __builtin_amdgcn_s_barrier();
    __builtin_amdgcn_sched_barrier(0);
}

// global -> LDS direct DMA, 16B per lane (dwordx4).
__device__ __forceinline__ void dma16(const void* g, void* l) {
    __builtin_amdgcn_global_load_lds(
        (const __attribute__((address_space(1))) unsigned int*)g,
        (__attribute__((address_space(3))) unsigned int*)l, 16, 0, 0);
}

// ---------------------------------------------------------------------------
// Kernel 1: W fp32 [k][n] (1024x128) -> Wt bf16 [n][k] (128x1024), x3.
// Softmax scale * log2(e) folded into Wq.
// ---------------------------------------------------------------------------
extern "C" __global__ __launch_bounds__(256) void head_wtrans(
    const float* __restrict__ Wq, const float* __restrict__ Wk,
    const float* __restrict__ Wv, u16* __restrict__ wt) {
    const float* W = (blockIdx.y == 0) ? Wq : (blockIdx.y == 1) ? Wk : Wv;
    const float scale =
        (blockIdx.y == 0) ? (0.08838834764831845f * 1.4426950408889634f) : 1.0f;
    u16* o = wt + (size_t)blockIdx.y * Cn * HSn;
    int tid = blockIdx.x * 256 + threadIdx.x;
    int n = tid >> 10, kk = tid & 1023;
    o[tid] = f2bf(W[kk * HSn + n] * scale);
}

// ---------------------------------------------------------------------------
// Kernel 2: FUSED QKV projection, round 9: FORCED register B-prefetch.
//   - x: DMA depth-2 into 2 x 8KB LDS bufs.
//   - wt: inline-asm global_load_dwordx4 into 2 named register sets
//     (depth-2, 48 VGPR guaranteed live), manual vmcnt.
//   - per phase: compute(t); wg_barrier; issue D(t+2)+B(t+2) [8 VMEM ops];
//     s_waitcnt vmcnt(8)  [= retire exactly phase (t-1)'s 8 issues ->
//     B(t+1),D(t+1) ready; phase-t issues stay in flight]; s_barrier; SBAR.
// 512 blocks x 256 thr (4 waves), BM=64, wave tile 64x96, 2 blocks/CU.
// ---------------------------------------------------------------------------
extern "C" __global__ __launch_bounds__(256) void head_proj(
    const float* __restrict__ x, const u16* __restrict__ wt, u16* __restrict__ qo,
    u16* __restrict__ ko, u16* __restrict__ vto) {
    __shared__ __align__(16) unsigned char sh[20480];  // 2x8KB bufs; tL overlay
    const int tid = threadIdx.x;
    const int w = tid >> 6, l = tid & 63, quad = l >> 4, ln = l & 15;
    const int bm0 = blockIdx.x * 64;
    const int n0 = w * 96;

    const f32x4 zero4 = {0.f, 0.f, 0.f, 0.f};
    f32x4 acc[4][6];
#pragma unroll
    for (int fi = 0; fi < 4; fi++)
#pragma unroll
        for (int ci = 0; ci < 6; ci++) acc[fi][ci] = zero4;

    // x DMA sources (pre-swizzled 16B slots) + linear LDS dests
    const float* xg[2];
    int xd[2];
#pragma unroll
    for (int p = 0; p < 2; p++) {
        int s = p * 256 + tid;          // 512 slots of 16B = 8 KB
        int row = s >> 3, slot = s & 7;
        int g = slot ^ (row & 7);
        xg[p] = x + (size_t)(bm0 + row) * Cn + g * 4;
        xd[p] = s * 16;
    }
    // A-fragment LDS read offsets (same XOR)
    int aoff[4];
#pragma unroll
    for (int fi = 0; fi < 4; fi++) {
        int row = fi * 16 + ln;
        aoff[fi] = row * 128 + (((2 * quad) ^ (row & 7)) * 16);
    }
    // B pointers: 6 cols per lane, fragment = contiguous 16B at [col][k]
    const u16* bp[6];
#pragma unroll
    for (int ci = 0; ci < 6; ci++)
        bp[ci] = wt + (size_t)(n0 + ci * 16 + ln) * Cn + quad * 8;

#define P_DMA(BUF, KT)                                       \
    do {                                                     \
        dma16(xg[0] + (KT) * 32, sh + (BUF) * 8192 + xd[0]); \
        dma16(xg[1] + (KT) * 32, sh + (BUF) * 8192 + xd[1]); \
    } while (0)

#define P_LOADB(DST, KT)                                 \
    do {                                                 \
        _Pragma("unroll") for (int ci = 0; ci < 6; ci++) \
            DST[ci] = gld16(bp[ci] + (KT) * 32);         \
    } while (0)

#define P_COMPUTE(BUF, BREG)                                               \
    do {                                                                   \
        const unsigned char* cb = sh + (BUF) * 8192;                       \
        bf16x8 af[4];                                                      \
        _Pragma("unroll") for (int fi = 0; fi < 4; fi++) {                 \
            f32x4 lo = *(const f32x4*)(cb + aoff[fi]);                     \
            f32x4 hi = *(const f32x4*)(cb + (aoff[fi] ^ 16));              \
            u32x4 tt;                                                      \
            tt[0] = cvt_pk_bf16(lo[0], lo[1]);                             \
            tt[1] = cvt_pk_bf16(lo[2], lo[3]);                             \
            tt[2] = cvt_pk_bf16(hi[0], hi[1]);                             \
            tt[3] = cvt_pk_bf16(hi[2], hi[3]);                             \
            af[fi] = __builtin_bit_cast(bf16x8, tt);                       \
        }                                                                  \
        __builtin_amdgcn_s_setprio(1);                                     \
        _Pragma("unroll") for (int ci = 0; ci < 6; ci++) {                 \
            bf16x8 bfr = __builtin_bit_cast(bf16x8, BREG[ci]);             \
            _Pragma("unroll") for (int fi = 0; fi < 4; fi++)               \
                acc[fi][ci] = __builtin_amdgcn_mfma_f32_16x16x32_bf16(     \
                    af[fi], bfr, acc[fi][ci], 0, 0, 0);                    \
        }                                                                  \
        __builtin_amdgcn_s_setprio(0);                                     \
    } while (0)

// end-of-phase sync: issue next loads already done by caller; wait leaves
// exactly this phase's 8 VMEM ops in flight (or drains on the tail).
#define P_SYNC(ISSUED)                                              \
    do {                                                            \
        SBAR;                                                       \
        if (ISSUED)                                                 \
            asm volatile("s_waitcnt vmcnt(8)" ::: "memory");        \
        else                                                        \
            asm volatile("s_waitcnt vmcnt(0)" ::: "memory");        \
        __builtin_amdgcn_s_barrier();                               \
        SBAR;                                                       \
    } while (0)

    u32x4 bA[6], bB[6];
    // prologue: D0,B0,D1,B1 (16 ops); need D0,B0 -> vmcnt(8).
    P_DMA(0, 0);
    P_LOADB(bA, 0);
    P_DMA(1, 1);
    P_LOADB(bB, 1);
    SBAR;
    asm volatile("s_waitcnt vmcnt(8)" ::: "memory");
    __builtin_amdgcn_s_barrier();
    SBAR;

    for (int t = 0; t < 32; t += 2) {
        // ---- phase t: buf0, bA ----
        P_COMPUTE(0, bA);
        wg_barrier();  // all waves' ds reads of buf0 done -> refill safe
        if (t + 2 < 32) {
            P_DMA(0, t + 2);
            P_LOADB(bA, t + 2);
        }
        P_SYNC(t + 2 < 32);
        // ---- phase t+1: buf1, bB ----
        P_COMPUTE(1, bB);
        if (t + 1 < 31) {
            wg_barrier();
            if (t + 3 < 32) {
                P_DMA(1, t + 3);
                P_LOADB(bB, t + 3);
            }
            P_SYNC(t + 3 < 32);
        }
    }
#undef P_DMA
#undef P_LOADB
#undef P_COMPUTE
#undef P_SYNC

    // ---- epilogue: q/k direct; v -> LDS transpose -> coalesced stores ----
    wg_barrier();  // buf reads all done; overlay tL
    u16* const tL = (u16*)sh;  // [128 d][80] u16 = 20480 B
#pragma unroll
    for (int ci = 0; ci < 6; ci++) {
        int col = n0 + ci * 16 + ln;
        int cin = col & 127;
        int sidx = col >> 7;  // wave-uniform per ci
#pragma unroll
        for (int fi = 0; fi < 4; fi++) {
            int grow = bm0 + fi * 16 + quad * 4;
            if (sidx == 0) {
#pragma unroll
                for (int r = 0; r < 4; r++)
                    qo[(size_t)(grow + r) * HSn + cin] = f2bf(acc[fi][ci][r]);
            } else if (sidx == 1) {
#pragma unroll
                for (int r = 0; r < 4; r++)
                    ko[(size_t)(grow + r) * HSn + cin] = f2bf(acc[fi][ci][r]);
            } else {
                u16x4 pk4;
#pragma unroll
                for (int r = 0; r < 4; r++) pk4[r] = f2bf(acc[fi][ci][r]);
                *(u16x4*)(tL + cin * 80 + (fi * 16 + quad * 4)) = pk4;
            }
        }
    }
    wg_barrier();
    {
        const int bb = bm0 >> 12, t0b = bm0 & 4095;
        const int dl = tid >> 3, tch = (tid & 7) * 8;  // 32 d rows x 64 t per pass
#pragma unroll
        for (int dp = 0; dp < 4; dp++) {
            int d = dp * 32 + dl;
            u16x8 vv = *(const u16x8*)(tL + d * 80 + tch);
            *(u16x8*)(vto + ((size_t)bb * HSn + d) * Tn + t0b + tch) = vv;
        }
    }
}

// ===========================================================================
// Kernel 3a: split-K flash chunk, QBLK=128 (round-6 version, ~48 us):
//   - 8 waves / 512 threads, 512 blocks (32 qbi x 8 b x 2 halves).
//   - static max (m=0), wave-private pL, 2 lgkm-only barriers/tile.
// LDS 54272 B -> 3 blocks/CU.
// ---------------------------------------------------------------------------
extern "C" __global__ __launch_bounds__(512) void head_flash_chunk(
    const u16* __restrict__ q, const u16* __restrict__ k, const u16* __restrict__ vt,
    u16* __restrict__ Opart, float* __restrict__ lsum) {
    __shared__ __align__(16) u16 kL[64 * 136];    // 17408 B
    __shared__ __align__(16) u16 vL[128 * 72];    // 18432 B
    __shared__ __align__(16) u16 pL[8 * 16 * 72]; // 18432 B
    const int tid = threadIdx.x;
    const int w = tid >> 6, l = tid & 63, quad = l >> 4, ln = l & 15;
    const int cid = blockIdx.x;
    const int grp = cid >> 4;  // 0..31
    const int qbi = (grp < 16) ? (31 - grp) : (grp - 16);
    const int b = (cid >> 1) & 7;
    const int half = cid & 1;
    const int q0 = qbi * 128;
    const int qrow = q0 + w * 16;

    const int rkBase = tid >> 4, ckK = tid & 15;  // 32 rows x 16 chunks
    const int rvBase = tid >> 3, ckV = tid & 7;   // 64 rows x 8 chunks

    bf16x8 qf[4];
#pragma unroll
    for (int ks = 0; ks < 4; ks++)
        qf[ks] = *(const bf16x8*)(q + ((size_t)b * Tn + qrow + ln) * HSn + ks * 32 +
                                  quad * 8);

    const f32x4 zero4 = {0.f, 0.f, 0.f, 0.f};
    float l2 = 0.f;
    const int qme = qrow + ln;
    const int clo = 2047 - (qme >> 1), chi = 2047 + ((qme + 1) >> 1);
    const int cloW0 = 2047 - (qrow >> 1);
    const int chiW0 = 2047 + ((qrow + 1) >> 1);
    const int cloMin = 2047 - ((qrow + 15) >> 1);
    const int chiMax = 2047 + ((qrow + 16) >> 1);
    f32x4 o[8];
#pragma unroll
    for (int dt = 0; dt < 8; dt++) o[dt] = zero4;

    const int qmax = q0 + 127;
    const int tlo = (2047 - (qmax >> 1)) >> 6;
    const int thi = (2047 + ((qmax + 1) >> 1)) >> 6;
    const int W = thi - tlo + 1;
    const int c0 = (W + 1) >> 1;
    const int kstart = half ? tlo + c0 : tlo;
    const int kend = half ? thi : tlo + c0 - 1;

    u16x8 pk[2], pv[2];
    {
        const int t0 = kstart * 64;
#pragma unroll
        for (int p = 0; p < 2; p++)
            pk[p] = *(const u16x8*)(k + ((size_t)b * Tn + t0 + p * 32 + rkBase) * HSn +
                                    ckK * 8);
#pragma unroll
        for (int p = 0; p < 2; p++)
            pv[p] = *(const u16x8*)(vt + ((size_t)b * HSn + p * 64 + rvBase) * Tn + t0 +
                                    ckV * 8);
    }

    for (int kt = kstart; kt <= kend; kt++) {
        const int t0 = kt * 64;
        wg_barrier();  // B1: prior tile's kL/vL reads complete everywhere
#pragma unroll
        for (int p = 0; p < 2; p++)
            *(u16x8*)(kL + (p * 32 + rkBase) * 136 + ckK * 8) = pk[p];
#pragma unroll
        for (int p = 0; p < 2; p++)
            *(u16x8*)(vL + (p * 64 + rvBase) * 72 + ckV * 8) = pv[p];
        if (kt < kend) {
            const int t1 = t0 + 64;
#pragma unroll
            for (int p = 0; p < 2; p++)
                pk[p] = *(const u16x8*)(k + ((size_t)b * Tn + t1 + p * 32 + rkBase) * HSn +
                                        ckK * 8);
#pragma unroll
            for (int p = 0; p < 2; p++)
                pv[p] = *(const u16x8*)(vt + ((size_t)b * HSn + p * 64 + rvBase) * Tn +
                                        t1 + ckV * 8);
        }
        wg_barrier();  // B2: staging visible (prefetch vmcnt NOT drained)

        const bool live = !((t0 + 63 < cloMin) || (t0 > chiMax));

        if (live) {
            f32x4 s[4];
#pragma unroll
            for (int nt = 0; nt < 4; nt++) s[nt] = zero4;
            __builtin_amdgcn_s_setprio(1);
#pragma unroll
            for (int nt = 0; nt < 4; nt++) {
                int R = nt * 16 + ln;
#pragma unroll
                for (int ks = 0; ks < 4; ks++) {
                    bf16x8 kf = *(const bf16x8*)(kL + R * 136 + (ks * 4 + quad) * 8);
                    s[nt] =
                        __builtin_amdgcn_mfma_f32_16x16x32_bf16(kf, qf[ks], s[nt], 0, 0, 0);
                }
            }
            __builtin_amdgcn_s_setprio(0);
            if (t0 < cloW0 || t0 + 63 > chiW0) {
#pragma unroll
                for (int nt = 0; nt < 4; nt++)
#pragma unroll
                    for (int r = 0; r < 4; r++) {
                        int t = t0 + nt * 16 + quad * 4 + r;
                        bool valid = (t >= clo) && (t <= chi);
                        s[nt][r] = valid ? s[nt][r] : -1e30f;
                    }
            }
            float ls = 0.f;
#pragma unroll
            for (int nt = 0; nt < 4; nt++) {
                float p0 = exp2f(s[nt][0]), p1 = exp2f(s[nt][1]);
                float p2 = exp2f(s[nt][2]), p3 = exp2f(s[nt][3]);
                ls += (p0 + p1) + (p2 + p3);
                u32x2 d;
                d.x = cvt_pk_bf16(p0, p1);
                d.y = cvt_pk_bf16(p2, p3);
                *(u32x2*)(pL + w * 1152 + ln * 72 + nt * 16 + quad * 4) = d;
            }
            l2 += ls;
            __builtin_amdgcn_s_setprio(1);
#pragma unroll
            for (int jt = 0; jt < 2; jt++) {
                bf16x8 pf = *(const bf16x8*)(pL + w * 1152 + ln * 72 + jt * 32 + quad * 8);
#pragma unroll
                for (int dt = 0; dt < 8; dt++) {
                    int R = dt * 16 + ln;
                    bf16x8 vf = *(const bf16x8*)(vL + R * 72 + (jt * 4 + quad) * 8);
                    o[dt] = __builtin_amdgcn_mfma_f32_16x16x32_bf16(pf, vf, o[dt], 0, 0, 0);
                }
            }
            __builtin_amdgcn_s_setprio(0);
        }
    }
    l2 += __shfl_xor(l2, 16, 64);
    l2 += __shfl_xor(l2, 32, 64);
#pragma unroll
    for (int dt = 0; dt < 8; dt++)
#pragma unroll
        for (int r = 0; r < 4; r++)
            Opart[((size_t)cid * 128 + w * 16 + quad * 4 + r) * HSn + dt * 16 + ln] =
                f2bf(o[dt][r]);
    if (l < 16) lsum[(size_t)cid * 128 + w * 16 + ln] = l2;
}

// ---------------------------------------------------------------------------
// Kernel 3b: combine 2 chunks per (b,qbi): out = (O0 + O1) / (l0 + l1).
// 512 blocks x 256 threads; each block does 64 rows x 128 cols.
// ---------------------------------------------------------------------------
extern "C" __global__ __launch_bounds__(256) void head_combine(
    const u16* __restrict__ Opart, const float* __restrict__ lsum,
    float* __restrict__ out) {
    const int bid = blockIdx.x;
    const int qb64 = bid >> 3, b = bid & 7;  // 64-row group 0..63
    const int tid = threadIdx.x;
    const int row = tid >> 2, dseg = (tid & 3) * 32;
    const int qbi = qb64 >> 1;
    const int inrow = (qb64 & 1) * 64 + row;  // row within 128-row chunk
    const int grp0 = (qbi >= 16) ? (31 - qbi) : (qbi + 16);
    const int cid0 = grp0 * 16 + b * 2;
    const size_t r0 = (size_t)cid0 * 128 + inrow, r1 = r0 + 128;
    float l0 = lsum[r0], l1 = lsum[r1];
    float inv = 1.0f / (l0 + l1);
    float* op = out + ((size_t)b * Tn + qb64 * 64 + row) * HSn + dseg;
    const u16* p0 = Opart + r0 * HSn + dseg;
    const u16* p1 = Opart + r1 * HSn + dseg;
#pragma unroll
    for (int j = 0; j < 4; j++) {
        u16x8 a = *(const u16x8*)(p0 + j * 8);
        u16x8 c = *(const u16x8*)(p1 + j * 8);
        f32x4 o1, o2;
#pragma unroll
        for (int e = 0; e < 4; e++) o1[e] = (bf2f(a[e]) + bf2f(c[e])) * inv;
#pragma unroll
        for (int e = 0; e < 4; e++) o2[e] = (bf2f(a[4 + e]) + bf2f(c[4 + e])) * inv;
        *(f32x4*)(op + j * 8) = o1;
        *(f32x4*)(op + j * 8 + 4) = o2;
    }
}

// ---------------------------------------------------------------------------
// Kernel 3-mono (fallback when ws too small for partials): round-5 flash.
// ---------------------------------------------------------------------------
extern "C" __global__ __launch_bounds__(256) void head_flash(
    const u16* __restrict__ q, const u16* __restrict__ k, const u16* __restrict__ vt,
    float* __restrict__ out) {
    __shared__ __align__(16) u16 kL[64 * 136];
    __shared__ __align__(16) u16 vL[128 * 72];
    __shared__ __align__(16) u16 pL[4 * 16 * 72];
    const int tid = threadIdx.x;
    const int w = tid >> 6, l = tid & 63, quad = l >> 4, ln = l & 15;
    const int bx = blockIdx.x;
    const int half = bx >> 8, idx = bx & 255;
    const int p5 = idx & 31, b = idx >> 5;
    const int qb = half ? p5 : 63 - p5;
    const int q0 = qb * 64;
    const int qrow = q0 + w * 16;
    const int rkBase = tid >> 4, ckK = tid & 15;
    const int rvBase = tid >> 3, ckV = tid & 7;

    bf16x8 qf[4];
#pragma unroll
    for (int ks = 0; ks < 4; ks++)
        qf[ks] = *(const bf16x8*)(q + ((size_t)b * Tn + qrow + ln) * HSn + ks * 32 +
                                  quad * 8);
    const f32x4 zero4 = {0.f, 0.f, 0.f, 0.f};
    float m2 = -1e30f, l2 = 0.f;
    const int qme = qrow + ln;
    const int clo = 2047 - (qme >> 1), chi = 2047 + ((qme + 1) >> 1);
    f32x4 o[8];
#pragma unroll
    for (int dt = 0; dt < 8; dt++) o[dt] = zero4;
    const int qmax = q0 + 63;
    const int tlo = (2047 - (qmax >> 1)) >> 6;
    const int thi = (2047 + ((qmax + 1) >> 1)) >> 6;

    u16x8 pk[4], pv[4];
    {
        const int t0 = tlo * 64;
#pragma unroll
        for (int p = 0; p < 4; p++)
            pk[p] = *(const u16x8*)(k + ((size_t)b * Tn + t0 + p * 16 + rkBase) * HSn +
                                    ckK * 8);
#pragma unroll
        for (int p = 0; p < 4; p++)
            pv[p] = *(const u16x8*)(vt + ((size_t)b * HSn + p * 32 + rvBase) * Tn + t0 +
                                    ckV * 8);
    }
    for (int kt = tlo; kt <= thi; kt++) {
        const int t0 = kt * 64;
        __syncthreads();
#pragma unroll
        for (int p = 0; p < 4; p++)
            *(u16x8*)(kL + (p * 16 + rkBase) * 136 + ckK * 8) = pk[p];
#pragma unroll
        for (int p = 0; p < 4; p++)
            *(u16x8*)(vL + (p * 32 + rvBase) * 72 + ckV * 8) = pv[p];
        if (kt < thi) {
            const int t1 = t0 + 64;
#pragma unroll
            for (int p = 0; p < 4; p++)
                pk[p] = *(const u16x8*)(k + ((size_t)b * Tn + t1 + p * 16 + rkBase) * HSn +
                                        ckK * 8);
#pragma unroll
            for (int p = 0; p < 4; p++)
                pv[p] = *(const u16x8*)(vt + ((size_t)b * HSn + p * 32 + rvBase) * Tn +
                                        t1 + ckV * 8);
        }
        __syncthreads();
        f32x4 s[4];
#pragma unroll
        for (int nt = 0; nt < 4; nt++) s[nt] = zero4;
#pragma unroll
        for (int nt = 0; nt < 4; nt++) {
            int R = nt * 16 + ln;
#pragma unroll
            for (int ks = 0; ks < 4; ks++) {
                bf16x8 kf = *(const bf16x8*)(kL + R * 136 + (ks * 4 + quad) * 8);
                s[nt] = __builtin_amdgcn_mfma_f32_16x16x32_bf16(kf, qf[ks], s[nt], 0, 0, 0);
            }
        }
#pragma unroll
        for (int nt = 0; nt < 4; nt++)
#pragma unroll
            for (int r = 0; r < 4; r++) {
                int t = t0 + nt * 16 + quad * 4 + r;
                bool valid = (t >= clo) && (t <= chi);
                s[nt][r] = valid ? s[nt][r] : -1e30f;
            }
        float mc = s[0][0];
#pragma unroll
        for (int nt = 0; nt < 4; nt++)
#pragma unroll
            for (int r = 0; r < 4; r++) mc = fmaxf(mc, s[nt][r]);
        mc = fmaxf(mc, __shfl_xor(mc, 16, 64));
        mc = fmaxf(mc, __shfl_xor(mc, 32, 64));
        float mn = fmaxf(m2, mc);
        float alpha = exp2f(m2 - mn);
        m2 = mn;
        float ls = 0.f;
#pragma unroll
        for (int nt = 0; nt < 4; nt++) {
            float p0 = exp2f(s[nt][0] - mn), p1 = exp2f(s[nt][1] - mn);
            float p2 = exp2f(s[nt][2] - mn), p3 = exp2f(s[nt][3] - mn);
            ls += (p0 + p1) + (p2 + p3);
            u32x2 d;
            d.x = cvt_pk_bf16(p0, p1);
            d.y = cvt_pk_bf16(p2, p3);
            *(u32x2*)(pL + w * 1152 + ln * 72 + nt * 16 + quad * 4) = d;
        }
        ls += __shfl_xor(ls, 16, 64);
        ls += __shfl_xor(ls, 32, 64);
        l2 = l2 * alpha + ls;
        float aR[4];
#pragma unroll
        for (int r = 0; r < 4; r++) aR[r] = __shfl(alpha, quad * 4 + r, 64);
#pragma unroll
        for (int dt = 0; dt < 8; dt++) {
            f32x4 oo = o[dt];
#pragma unroll
            for (int r = 0; r < 4; r++) oo[r] *= aR[r];
            o[dt] = oo;
        }
#pragma unroll
        for (int jt = 0; jt < 2; jt++) {
            bf16x8 pf = *(const bf16x8*)(pL + w * 1152 + ln * 72 + jt * 32 + quad * 8);
#pragma unroll
            for (int dt = 0; dt < 8; dt++) {
                int R = dt * 16 + ln;
                bf16x8 vf = *(const bf16x8*)(vL + R * 72 + (jt * 4 + quad) * 8);
                o[dt] = __builtin_amdgcn_mfma_f32_16x16x32_bf16(pf, vf, o[dt], 0, 0, 0);
            }
        }
    }
    float inv = 1.0f / l2;
    float rl[4];
#pragma unroll
    for (int r = 0; r < 4; r++) rl[r] = __shfl(inv, quad * 4 + r, 64);
#pragma unroll
    for (int dt = 0; dt < 8; dt++)
#pragma unroll
        for (int r = 0; r < 4; r++) {
            int row = qrow + quad * 4 + r;
            out[((size_t)b * Tn + row) * HSn + dt * 16 + ln] = o[dt][r] * rl[r];
        }
}

// ---------------------------------------------------------------------------
extern "C" void kernel_launch(void* const* d_in, const int* in_sizes, int n_in,
                              void* d_out, int out_size, void* d_ws, size_t ws_size,
                              hipStream_t stream) {
    const float* x = (const float*)d_in[0];
    const float* Wq = (const float*)d_in[1];
    const float* Wk = (const float*)d_in[2];
    const float* Wv = (const float*)d_in[3];
    float* outp = (float*)d_out;
    char* ws = (char*)d_ws;
    // ws: wt @0 (768KB), q @1MB, k @9MB, vt @17MB (8MB each),
    // Opart bf16 @25MB (16.78MB), lsum fp32 @42MB (256KB) -> needs ~43MB.
    u16* wt = (u16*)(ws);
    u16* qb = (u16*)(ws + (1u << 20));
    u16* kb = (u16*)(ws + (9u << 20));
    u16* vtb = (u16*)(ws + (17u << 20));
    u16* Opart = (u16*)(ws + (25u << 20));
    float* lsum = (float*)(ws + (42u << 20));

    head_wtrans<<<dim3(512, 3), 256, 0, stream>>>(Wq, Wk, Wv, wt);
    head_proj<<<dim3(512), 256, 0, stream>>>(x, wt, qb, kb, vtb);
    if (ws_size >= (44ull << 20)) {
        head_flash_chunk<<<dim3(512), 512, 0, stream>>>(qb, kb, vtb, Opart, lsum);
        head_combine<<<dim3(512), 256, 0, stream>>>(Opart, lsum, outp);
    } else {
        head_flash<<<dim3(512), 256, 0, stream>>>(qb, kb, vtb, outp);
    }
}

// Round 10
// 296.154 us; speedup vs baseline: 1.0565x; 1.0565x over previous
//
#include <hip/hip_runtime.h>

typedef unsigned short u16;
typedef __attribute__((ext_vector_type(8))) short bf16x8;
typedef __attribute__((ext_vector_type(8))) unsigned short u16x8;
typedef __attribute__((ext_vector_type(4))) float f32x4;
typedef __attribute__((ext_vector_type(4))) unsigned short u16x4;
typedef __attribute__((ext_vector_type(2))) unsigned int u32x2;

#define Bn 8
#define Tn 4096
#define Cn 1024
#define HSn 128

#define SBAR __builtin_amdgcn_sched_barrier(0)

__device__ __forceinline__ float bf2f(u16 b) {
    unsigned u = ((unsigned)b) << 16;
    return __builtin_bit_cast(float, u);
}
// HW packed f32->bf16 (RNE), 1 VALU op for 2 values. No builtin on gfx950.
__device__ __forceinline__ unsigned cvt_pk_bf16(float a, float b) {
    unsigned r;
    asm("v_cvt_pk_bf16_f32 %0, %1, %2" : "=v"(r) : "v"(a), "v"(b));
    return r;
}
__device__ __forceinline__ u16 f2bf(float f) { return (u16)cvt_pk_bf16(f, f); }

// Workgroup barrier WITHOUT vmcnt drain: LDS visibility needs lgkmcnt(0) only.
// Outstanding global register loads (prefetch) stay in flight across the
// barrier; compiler inserts vmcnt waits at their use.
__device__ __forceinline__ void wg_barrier() {
    __builtin_amdgcn_sched_barrier(0);
    asm volatile("s_waitcnt lgkmcnt(0)" ::: "memory");
    __builtin_amdgcn_s_barrier();
    __builtin_amdgcn_sched_barrier(0);
}

// ---------------------------------------------------------------------------
// Kernel 1: W fp32 [k][n] (1024x128) -> Wt bf16 [n][k] (128x1024), x3.
// Softmax scale * log2(e) folded into Wq.
// ---------------------------------------------------------------------------
extern "C" __global__ __launch_bounds__(256) void head_wtrans(
    const float* __restrict__ Wq, const float* __restrict__ Wk,
    const float* __restrict__ Wv, u16* __restrict__ wt) {
    const float* W = (blockIdx.y == 0) ? Wq : (blockIdx.y == 1) ? Wk : Wv;
    const float scale =
        (blockIdx.y == 0) ? (0.08838834764831845f * 1.4426950408889634f) : 1.0f;
    u16* o = wt + (size_t)blockIdx.y * Cn * HSn;
    int tid = blockIdx.x * 256 + threadIdx.x;
    int n = tid >> 10, kk = tid & 1023;
    o[tid] = f2bf(W[kk * HSn + n] * scale);
}

// ---------------------------------------------------------------------------
// Kernel 2: FUSED QKV projection — EXACT round-2 kernel (best measured proj
// of the session, ~56 us by books). BM=128, LDS-staged x+wt with register
// prefetch across lgkm-only barriers, V^T via LDS transpose. All later
// rewrites (BM=64 / DMA 2-deep / DMA 3-deep / wt-unstaged / asm-forced)
// measured 64-150 us. Reverted verbatim.
// ---------------------------------------------------------------------------
extern "C" __global__ __launch_bounds__(256, 1) void head_proj(
    const float* __restrict__ x, const u16* __restrict__ wt, u16* __restrict__ qo,
    u16* __restrict__ ko, u16* __restrict__ vto) {
    // overlay: staging aL[128*40] + bL[3*128*40] = 20480 u16; epilogue reuses
    // the same memory as tL[128][136] (17408 u16) for the V transpose.
    __shared__ __align__(16) u16 sh[20480];
    u16* const aL = sh;
    u16* const bL = sh + 128 * 40;
    const int tid = threadIdx.x;
    const int w = tid >> 6, l = tid & 63, quad = l >> 4, ln = l & 15;
    const int bm0 = blockIdx.x * 128;

    const f32x4 zero4 = {0.f, 0.f, 0.f, 0.f};
    f32x4 acc[3][4][4];
#pragma unroll
    for (int s = 0; s < 3; s++)
#pragma unroll
        for (int i = 0; i < 4; i++)
#pragma unroll
            for (int j = 0; j < 4; j++) acc[s][i][j] = zero4;

    const int m0w = (w & 1) * 64, n0w = (w >> 1) * 64;

    f32x4 xp[4];
    u16x8 wp[3][2];
    const int xrow[4] = {tid >> 3, (256 + tid) >> 3, (512 + tid) >> 3, (768 + tid) >> 3};
    const int xch = tid & 7;
    const int wrow[2] = {tid >> 2, (256 + tid) >> 2};
    const int wch = tid & 3;

#pragma unroll
    for (int p = 0; p < 4; p++)
        xp[p] = *(const f32x4*)(x + ((size_t)(bm0 + xrow[p])) * Cn + xch * 4);
#pragma unroll
    for (int s = 0; s < 3; s++)
#pragma unroll
        for (int p = 0; p < 2; p++)
            wp[s][p] = *(const u16x8*)(wt + (size_t)s * Cn * HSn + (size_t)wrow[p] * Cn +
                                       wch * 8);

    for (int kt = 0; kt < Cn / 32; kt++) {
        wg_barrier();
#pragma unroll
        for (int p = 0; p < 4; p++) {
            u32x2 d;
            d.x = cvt_pk_bf16(xp[p][0], xp[p][1]);
            d.y = cvt_pk_bf16(xp[p][2], xp[p][3]);
            *(u32x2*)(aL + xrow[p] * 40 + xch * 4) = d;
        }
#pragma unroll
        for (int s = 0; s < 3; s++)
#pragma unroll
            for (int p = 0; p < 2; p++)
                *(u16x8*)(bL + s * 5120 + wrow[p] * 40 + wch * 8) = wp[s][p];
        if (kt + 1 < Cn / 32) {
            const int kn = (kt + 1) * 32;
#pragma unroll
            for (int p = 0; p < 4; p++)
                xp[p] = *(const f32x4*)(x + ((size_t)(bm0 + xrow[p])) * Cn + kn + xch * 4);
#pragma unroll
            for (int s = 0; s < 3; s++)
#pragma unroll
                for (int p = 0; p < 2; p++)
                    wp[s][p] = *(const u16x8*)(wt + (size_t)s * Cn * HSn +
                                               (size_t)wrow[p] * Cn + kn + wch * 8);
        }
        wg_barrier();
        bf16x8 af[4];
#pragma unroll
        for (int mi = 0; mi < 4; mi++)
            af[mi] = *(const bf16x8*)(aL + (m0w + mi * 16 + ln) * 40 + quad * 8);
#pragma unroll
        for (int s = 0; s < 3; s++) {
            bf16x8 bf[4];
#pragma unroll
            for (int ni = 0; ni < 4; ni++)
                bf[ni] =
                    *(const bf16x8*)(bL + s * 5120 + (n0w + ni * 16 + ln) * 40 + quad * 8);
#pragma unroll
            for (int mi = 0; mi < 4; mi++)
#pragma unroll
                for (int ni = 0; ni < 4; ni++)
                    acc[s][mi][ni] = __builtin_amdgcn_mfma_f32_16x16x32_bf16(
                        af[mi], bf[ni], acc[s][mi][ni], 0, 0, 0);
        }
    }
    // q/k: row-major stores.
#pragma unroll
    for (int mi = 0; mi < 4; mi++)
#pragma unroll
        for (int ni = 0; ni < 4; ni++)
#pragma unroll
            for (int r = 0; r < 4; r++) {
                int grow = bm0 + m0w + mi * 16 + quad * 4 + r;
                int col = n0w + ni * 16 + ln;
                qo[(size_t)grow * HSn + col] = f2bf(acc[0][mi][ni][r]);
                ko[(size_t)grow * HSn + col] = f2bf(acc[1][mi][ni][r]);
            }
    // V: transpose the block's 128(t) x 128(d) tile through LDS, then store
    // vt[b][d][t] with contiguous 16B runs along t (fully coalesced).
    wg_barrier();  // all staging reads done -> safe to overlay tL
    u16* const tL = sh;  // [128 d][136] u16
#pragma unroll
    for (int mi = 0; mi < 4; mi++)
#pragma unroll
        for (int ni = 0; ni < 4; ni++) {
            int col = n0w + ni * 16 + ln;              // d
            int trow0 = m0w + mi * 16 + quad * 4;      // t within tile
            u16x4 pk4;
#pragma unroll
            for (int r = 0; r < 4; r++) pk4[r] = f2bf(acc[2][mi][ni][r]);
            *(u16x4*)(tL + col * 136 + trow0) = pk4;
        }
    wg_barrier();
    {
        const int bb = bm0 >> 12, t0b = bm0 & 4095;
        const int dl = tid >> 4, tch = (tid & 15) * 8;
#pragma unroll
        for (int db = 0; db < 8; db++) {
            int d = db * 16 + dl;
            u16x8 vv = *(const u16x8*)(tL + d * 136 + tch);
            *(u16x8*)(vto + ((size_t)bb * HSn + d) * Tn + t0b + tch) = vv;
        }
    }
}

// ===========================================================================
// Kernel 3a: split-K flash chunk, QBLK=128 (round-6 version, ~48 us):
//   - 8 waves / 512 threads, 512 blocks (32 qbi x 8 b x 2 halves).
//   - static max (m=0), wave-private pL, 2 lgkm-only barriers/tile.
// LDS 54272 B.
// ---------------------------------------------------------------------------
extern "C" __global__ __launch_bounds__(512) void head_flash_chunk(
    const u16* __restrict__ q, const u16* __restrict__ k, const u16* __restrict__ vt,
    u16* __restrict__ Opart, float* __restrict__ lsum) {
    __shared__ __align__(16) u16 kL[64 * 136];    // 17408 B
    __shared__ __align__(16) u16 vL[128 * 72];    // 18432 B
    __shared__ __align__(16) u16 pL[8 * 16 * 72]; // 18432 B
    const int tid = threadIdx.x;
    const int w = tid >> 6, l = tid & 63, quad = l >> 4, ln = l & 15;
    const int cid = blockIdx.x;
    const int grp = cid >> 4;  // 0..31
    const int qbi = (grp < 16) ? (31 - grp) : (grp - 16);
    const int b = (cid >> 1) & 7;
    const int half = cid & 1;
    const int q0 = qbi * 128;
    const int qrow = q0 + w * 16;

    const int rkBase = tid >> 4, ckK = tid & 15;  // 32 rows x 16 chunks
    const int rvBase = tid >> 3, ckV = tid & 7;   // 64 rows x 8 chunks

    bf16x8 qf[4];
#pragma unroll
    for (int ks = 0; ks < 4; ks++)
        qf[ks] = *(const bf16x8*)(q + ((size_t)b * Tn + qrow + ln) * HSn + ks * 32 +
                                  quad * 8);

    const f32x4 zero4 = {0.f, 0.f, 0.f, 0.f};
    float l2 = 0.f;
    const int qme = qrow + ln;
    const int clo = 2047 - (qme >> 1), chi = 2047 + ((qme + 1) >> 1);
    const int cloW0 = 2047 - (qrow >> 1);
    const int chiW0 = 2047 + ((qrow + 1) >> 1);
    const int cloMin = 2047 - ((qrow + 15) >> 1);
    const int chiMax = 2047 + ((qrow + 16) >> 1);
    f32x4 o[8];
#pragma unroll
    for (int dt = 0; dt < 8; dt++) o[dt] = zero4;

    const int qmax = q0 + 127;
    const int tlo = (2047 - (qmax >> 1)) >> 6;
    const int thi = (2047 + ((qmax + 1) >> 1)) >> 6;
    const int W = thi - tlo + 1;
    const int c0 = (W + 1) >> 1;
    const int kstart = half ? tlo + c0 : tlo;
    const int kend = half ? thi : tlo + c0 - 1;

    u16x8 pk[2], pv[2];
    {
        const int t0 = kstart * 64;
#pragma unroll
        for (int p = 0; p < 2; p++)
            pk[p] = *(const u16x8*)(k + ((size_t)b * Tn + t0 + p * 32 + rkBase) * HSn +
                                    ckK * 8);
#pragma unroll
        for (int p = 0; p < 2; p++)
            pv[p] = *(const u16x8*)(vt + ((size_t)b * HSn + p * 64 + rvBase) * Tn + t0 +
                                    ckV * 8);
    }

    for (int kt = kstart; kt <= kend; kt++) {
        const int t0 = kt * 64;
        wg_barrier();  // B1: prior tile's kL/vL reads complete everywhere
#pragma unroll
        for (int p = 0; p < 2; p++)
            *(u16x8*)(kL + (p * 32 + rkBase) * 136 + ckK * 8) = pk[p];
#pragma unroll
        for (int p = 0; p < 2; p++)
            *(u16x8*)(vL + (p * 64 + rvBase) * 72 + ckV * 8) = pv[p];
        if (kt < kend) {
            const int t1 = t0 + 64;
#pragma unroll
            for (int p = 0; p < 2; p++)
                pk[p] = *(const u16x8*)(k + ((size_t)b * Tn + t1 + p * 32 + rkBase) * HSn +
                                        ckK * 8);
#pragma unroll
            for (int p = 0; p < 2; p++)
                pv[p] = *(const u16x8*)(vt + ((size_t)b * HSn + p * 64 + rvBase) * Tn +
                                        t1 + ckV * 8);
        }
        wg_barrier();  // B2: staging visible (prefetch vmcnt NOT drained)

        const bool live = !((t0 + 63 < cloMin) || (t0 > chiMax));

        if (live) {
            f32x4 s[4];
#pragma unroll
            for (int nt = 0; nt < 4; nt++) s[nt] = zero4;
            __builtin_amdgcn_s_setprio(1);
#pragma unroll
            for (int nt = 0; nt < 4; nt++) {
                int R = nt * 16 + ln;
#pragma unroll
                for (int ks = 0; ks < 4; ks++) {
                    bf16x8 kf = *(const bf16x8*)(kL + R * 136 + (ks * 4 + quad) * 8);
                    s[nt] =
                        __builtin_amdgcn_mfma_f32_16x16x32_bf16(kf, qf[ks], s[nt], 0, 0, 0);
                }
            }
            __builtin_amdgcn_s_setprio(0);
            if (t0 < cloW0 || t0 + 63 > chiW0) {
#pragma unroll
                for (int nt = 0; nt < 4; nt++)
#pragma unroll
                    for (int r = 0; r < 4; r++) {
                        int t = t0 + nt * 16 + quad * 4 + r;
                        bool valid = (t >= clo) && (t <= chi);
                        s[nt][r] = valid ? s[nt][r] : -1e30f;
                    }
            }
            float ls = 0.f;
#pragma unroll
            for (int nt = 0; nt < 4; nt++) {
                float p0 = exp2f(s[nt][0]), p1 = exp2f(s[nt][1]);
                float p2 = exp2f(s[nt][2]), p3 = exp2f(s[nt][3]);
                ls += (p0 + p1) + (p2 + p3);
                u32x2 d;
                d.x = cvt_pk_bf16(p0, p1);
                d.y = cvt_pk_bf16(p2, p3);
                *(u32x2*)(pL + w * 1152 + ln * 72 + nt * 16 + quad * 4) = d;
            }
            l2 += ls;
            __builtin_amdgcn_s_setprio(1);
#pragma unroll
            for (int jt = 0; jt < 2; jt++) {
                bf16x8 pf = *(const bf16x8*)(pL + w * 1152 + ln * 72 + jt * 32 + quad * 8);
#pragma unroll
                for (int dt = 0; dt < 8; dt++) {
                    int R = dt * 16 + ln;
                    bf16x8 vf = *(const bf16x8*)(vL + R * 72 + (jt * 4 + quad) * 8);
                    o[dt] = __builtin_amdgcn_mfma_f32_16x16x32_bf16(pf, vf, o[dt], 0, 0, 0);
                }
            }
            __builtin_amdgcn_s_setprio(0);
        }
    }
    l2 += __shfl_xor(l2, 16, 64);
    l2 += __shfl_xor(l2, 32, 64);
#pragma unroll
    for (int dt = 0; dt < 8; dt++)
#pragma unroll
        for (int r = 0; r < 4; r++)
            Opart[((size_t)cid * 128 + w * 16 + quad * 4 + r) * HSn + dt * 16 + ln] =
                f2bf(o[dt][r]);
    if (l < 16) lsum[(size_t)cid * 128 + w * 16 + ln] = l2;
}

// ---------------------------------------------------------------------------
// Kernel 3b: combine 2 chunks per (b,qbi): out = (O0 + O1) / (l0 + l1).
// 512 blocks x 256 threads; each block does 64 rows x 128 cols.
// ---------------------------------------------------------------------------
extern "C" __global__ __launch_bounds__(256) void head_combine(
    const u16* __restrict__ Opart, const float* __restrict__ lsum,
    float* __restrict__ out) {
    const int bid = blockIdx.x;
    const int qb64 = bid >> 3, b = bid & 7;  // 64-row group 0..63
    const int tid = threadIdx.x;
    const int row = tid >> 2, dseg = (tid & 3) * 32;
    const int qbi = qb64 >> 1;
    const int inrow = (qb64 & 1) * 64 + row;  // row within 128-row chunk
    const int grp0 = (qbi >= 16) ? (31 - qbi) : (qbi + 16);
    const int cid0 = grp0 * 16 + b * 2;
    const size_t r0 = (size_t)cid0 * 128 + inrow, r1 = r0 + 128;
    float l0 = lsum[r0], l1 = lsum[r1];
    float inv = 1.0f / (l0 + l1);
    float* op = out + ((size_t)b * Tn + qb64 * 64 + row) * HSn + dseg;
    const u16* p0 = Opart + r0 * HSn + dseg;
    const u16* p1 = Opart + r1 * HSn + dseg;
#pragma unroll
    for (int j = 0; j < 4; j++) {
        u16x8 a = *(const u16x8*)(p0 + j * 8);
        u16x8 c = *(const u16x8*)(p1 + j * 8);
        f32x4 o1, o2;
#pragma unroll
        for (int e = 0; e < 4; e++) o1[e] = (bf2f(a[e]) + bf2f(c[e])) * inv;
#pragma unroll
        for (int e = 0; e < 4; e++) o2[e] = (bf2f(a[4 + e]) + bf2f(c[4 + e])) * inv;
        *(f32x4*)(op + j * 8) = o1;
        *(f32x4*)(op + j * 8 + 4) = o2;
    }
}

// ---------------------------------------------------------------------------
// Kernel 3-mono (fallback when ws too small for partials): round-5 flash.
// ---------------------------------------------------------------------------
extern "C" __global__ __launch_bounds__(256) void head_flash(
    const u16* __restrict__ q, const u16* __restrict__ k, const u16* __restrict__ vt,
    float* __restrict__ out) {
    __shared__ __align__(16) u16 kL[64 * 136];
    __shared__ __align__(16) u16 vL[128 * 72];
    __shared__ __align__(16) u16 pL[4 * 16 * 72];
    const int tid = threadIdx.x;
    const int w = tid >> 6, l = tid & 63, quad = l >> 4, ln = l & 15;
    const int bx = blockIdx.x;
    const int half = bx >> 8, idx = bx & 255;
    const int p5 = idx & 31, b = idx >> 5;
    const int qb = half ? p5 : 63 - p5;
    const int q0 = qb * 64;
    const int qrow = q0 + w * 16;
    const int rkBase = tid >> 4, ckK = tid & 15;
    const int rvBase = tid >> 3, ckV = tid & 7;

    bf16x8 qf[4];
#pragma unroll
    for (int ks = 0; ks < 4; ks++)
        qf[ks] = *(const bf16x8*)(q + ((size_t)b * Tn + qrow + ln) * HSn + ks * 32 +
                                  quad * 8);
    const f32x4 zero4 = {0.f, 0.f, 0.f, 0.f};
    float m2 = -1e30f, l2 = 0.f;
    const int qme = qrow + ln;
    const int clo = 2047 - (qme >> 1), chi = 2047 + ((qme + 1) >> 1);
    f32x4 o[8];
#pragma unroll
    for (int dt = 0; dt < 8; dt++) o[dt] = zero4;
    const int qmax = q0 + 63;
    const int tlo = (2047 - (qmax >> 1)) >> 6;
    const int thi = (2047 + ((qmax + 1) >> 1)) >> 6;

    u16x8 pk[4], pv[4];
    {
        const int t0 = tlo * 64;
#pragma unroll
        for (int p = 0; p < 4; p++)
            pk[p] = *(const u16x8*)(k + ((size_t)b * Tn + t0 + p * 16 + rkBase) * HSn +
                                    ckK * 8);
#pragma unroll
        for (int p = 0; p < 4; p++)
            pv[p] = *(const u16x8*)(vt + ((size_t)b * HSn + p * 32 + rvBase) * Tn + t0 +
                                    ckV * 8);
    }
    for (int kt = tlo; kt <= thi; kt++) {
        const int t0 = kt * 64;
        __syncthreads();
#pragma unroll
        for (int p = 0; p < 4; p++)
            *(u16x8*)(kL + (p * 16 + rkBase) * 136 + ckK * 8) = pk[p];
#pragma unroll
        for (int p = 0; p < 4; p++)
            *(u16x8*)(vL + (p * 32 + rvBase) * 72 + ckV * 8) = pv[p];
        if (kt < thi) {
            const int t1 = t0 + 64;
#pragma unroll
            for (int p = 0; p < 4; p++)
                pk[p] = *(const u16x8*)(k + ((size_t)b * Tn + t1 + p * 16 + rkBase) * HSn +
                                        ckK * 8);
#pragma unroll
            for (int p = 0; p < 4; p++)
                pv[p] = *(const u16x8*)(vt + ((size_t)b * HSn + p * 32 + rvBase) * Tn +
                                        t1 + ckV * 8);
        }
        __syncthreads();
        f32x4 s[4];
#pragma unroll
        for (int nt = 0; nt < 4; nt++) s[nt] = zero4;
#pragma unroll
        for (int nt = 0; nt < 4; nt++) {
            int R = nt * 16 + ln;
#pragma unroll
            for (int ks = 0; ks < 4; ks++) {
                bf16x8 kf = *(const bf16x8*)(kL + R * 136 + (ks * 4 + quad) * 8);
                s[nt] = __builtin_amdgcn_mfma_f32_16x16x32_bf16(kf, qf[ks], s[nt], 0, 0, 0);
            }
        }
#pragma unroll
        for (int nt = 0; nt < 4; nt++)
#pragma unroll
            for (int r = 0; r < 4; r++) {
                int t = t0 + nt * 16 + quad * 4 + r;
                bool valid = (t >= clo) && (t <= chi);
                s[nt][r] = valid ? s[nt][r] : -1e30f;
            }
        float mc = s[0][0];
#pragma unroll
        for (int nt = 0; nt < 4; nt++)
#pragma unroll
            for (int r = 0; r < 4; r++) mc = fmaxf(mc, s[nt][r]);
        mc = fmaxf(mc, __shfl_xor(mc, 16, 64));
        mc = fmaxf(mc, __shfl_xor(mc, 32, 64));
        float mn = fmaxf(m2, mc);
        float alpha = exp2f(m2 - mn);
        m2 = mn;
        float ls = 0.f;
#pragma unroll
        for (int nt = 0; nt < 4; nt++) {
            float p0 = exp2f(s[nt][0] - mn), p1 = exp2f(s[nt][1] - mn);
            float p2 = exp2f(s[nt][2] - mn), p3 = exp2f(s[nt][3] - mn);
            ls += (p0 + p1) + (p2 + p3);
            u32x2 d;
            d.x = cvt_pk_bf16(p0, p1);
            d.y = cvt_pk_bf16(p2, p3);
            *(u32x2*)(pL + w * 1152 + ln * 72 + nt * 16 + quad * 4) = d;
        }
        ls += __shfl_xor(ls, 16, 64);
        ls += __shfl_xor(ls, 32, 64);
        l2 = l2 * alpha + ls;
        float aR[4];
#pragma unroll
        for (int r = 0; r < 4; r++) aR[r] = __shfl(alpha, quad * 4 + r, 64);
#pragma unroll
        for (int dt = 0; dt < 8; dt++) {
            f32x4 oo = o[dt];
#pragma unroll
            for (int r = 0; r < 4; r++) oo[r] *= aR[r];
            o[dt] = oo;
        }
#pragma unroll
        for (int jt = 0; jt < 2; jt++) {
            bf16x8 pf = *(const bf16x8*)(pL + w * 1152 + ln * 72 + jt * 32 + quad * 8);
#pragma unroll
            for (int dt = 0; dt < 8; dt++) {
                int R = dt * 16 + ln;
                bf16x8 vf = *(const bf16x8*)(vL + R * 72 + (jt * 4 + quad) * 8);
                o[dt] = __builtin_amdgcn_mfma_f32_16x16x32_bf16(pf, vf, o[dt], 0, 0, 0);
            }
        }
    }
    float inv = 1.0f / l2;
    float rl[4];
#pragma unroll
    for (int r = 0; r < 4; r++) rl[r] = __shfl(inv, quad * 4 + r, 64);
#pragma unroll
    for (int dt = 0; dt < 8; dt++)
#pragma unroll
        for (int r = 0; r < 4; r++) {
            int row = qrow + quad * 4 + r;
            out[((size_t)b * Tn + row) * HSn + dt * 16 + ln] = o[dt][r] * rl[r];
        }
}

// ---------------------------------------------------------------------------
extern "C" void kernel_launch(void* const* d_in, const int* in_sizes, int n_in,
                              void* d_out, int out_size, void* d_ws, size_t ws_size,
                              hipStream_t stream) {
    const float* x = (const float*)d_in[0];
    const float* Wq = (const float*)d_in[1];
    const float* Wk = (const float*)d_in[2];
    const float* Wv = (const float*)d_in[3];
    float* outp = (float*)d_out;
    char* ws = (char*)d_ws;
    // ws: wt @0 (768KB), q @1MB, k @9MB, vt @17MB (8MB each),
    // Opart bf16 @25MB (16.78MB), lsum fp32 @42MB (256KB) -> needs ~43MB.
    u16* wt = (u16*)(ws);
    u16* qb = (u16*)(ws + (1u << 20));
    u16* kb = (u16*)(ws + (9u << 20));
    u16* vtb = (u16*)(ws + (17u << 20));
    u16* Opart = (u16*)(ws + (25u << 20));
    float* lsum = (float*)(ws + (42u << 20));

    head_wtrans<<<dim3(512, 3), 256, 0, stream>>>(Wq, Wk, Wv, wt);
    head_proj<<<dim3(256), 256, 0, stream>>>(x, wt, qb, kb, vtb);
    if (ws_size >= (44ull << 20)) {
        head_flash_chunk<<<dim3(512), 512, 0, stream>>>(qb, kb, vtb, Opart, lsum);
        head_combine<<<dim3(512), 256, 0, stream>>>(Opart, lsum, outp);
    } else {
        head_flash<<<dim3(512), 256, 0, stream>>>(qb, kb, vtb, outp);
    }
}